// Round 1
// baseline (611.341 us; speedup 1.0000x reference)
//
#include <hip/hip_runtime.h>
#include <hip/hip_bf16.h>
#include <stdint.h>

// y = X(8192x4096) @ W(4096x3072) + b, then rotor quantizer:
// out = fwht(clip(round(fwht(pad(y))/64/0.25),-8,7)*0.25)/64, first 3072 cols.
//
// GEMM: single fp16 MFMA (32x32x16), fp32 accumulate. fp16 roundoff gives
// y-error std ~4e-4 -> ~5 quant-level flips/row -> absmax ~0.06 < 0.11 thr.
//
// R1: pipelined schedule (T3+T4+T5+T1). BK=32, quad-buffered LDS, stage tile
// t+3 while computing tile t, counted s_waitcnt vmcnt(8) + ONE raw s_barrier
// per K-tile (loads stay in flight across the barrier - no vmcnt(0) drain in
// the main loop). setprio around MFMA cluster; bijective XCD block swizzle.

#define GM 8192
#define GN 3072
#define GK 4096
#define NT 128   // GK / 32 k-tiles

typedef _Float16 f16;
typedef __attribute__((ext_vector_type(8))) _Float16 f16x8;   // 4 VGPRs
typedef __attribute__((ext_vector_type(16))) float f32x16;

__device__ __forceinline__ void gl2lds16(const void* g, void* l) {
    __builtin_amdgcn_global_load_lds(
        (const __attribute__((address_space(1))) void*)g,
        (__attribute__((address_space(3))) void*)l, 16, 0, 0);
}

// ---------------- cast / transpose pre-passes ----------------

struct alignas(16) H8 { f16 v[8]; };

__global__ __launch_bounds__(256) void split_x_kernel(
    const float* __restrict__ X, f16* __restrict__ Xh)
{
    const size_t i = ((size_t)blockIdx.x * 256 + threadIdx.x) * 8;
    const float4 a = *(const float4*)(X + i);
    const float4 b = *(const float4*)(X + i + 4);
    H8 h;
    h.v[0] = (f16)a.x; h.v[1] = (f16)a.y; h.v[2] = (f16)a.z; h.v[3] = (f16)a.w;
    h.v[4] = (f16)b.x; h.v[5] = (f16)b.y; h.v[6] = (f16)b.z; h.v[7] = (f16)b.w;
    *(H8*)(Xh + i) = h;
}

// W: (4096 k) x (3072 n) row-major -> WT: (3072 n) x (4096 k) fp16
__global__ __launch_bounds__(256) void split_wt_kernel(
    const float* __restrict__ W, f16* __restrict__ WT)
{
    __shared__ float tile[32][33];
    const int nt = blockIdx.x * 32;
    const int kt = blockIdx.y * 32;
    const int tx = threadIdx.x & 31;
    const int ty = threadIdx.x >> 5;   // 0..7
    #pragma unroll
    for (int r = 0; r < 4; ++r)
        tile[ty + 8 * r][tx] = W[(size_t)(kt + ty + 8 * r) * GN + nt + tx];
    __syncthreads();
    #pragma unroll
    for (int r = 0; r < 4; ++r)
        WT[(size_t)(nt + ty + 8 * r) * GK + kt + tx] = (f16)tile[tx][ty + 8 * r];
}

// ---------------- fp16 MFMA GEMM (32x32x16), 128x128 tile, BK=32, 4-deep ----
// LDS rows: 32 halfs (64 B) = 4 x 16-B slots, XOR-swizzled:
//   phys = slot ^ (row&3) ^ ((row>>2)&3)
// -> any 8 consecutive rows at a fixed logical slot cover all 32 banks exactly
// once (conflict-free ds_read_b128). gl2lds writes linearly; the inverse
// swizzle is applied to the GLOBAL source column (rule: linear LDS dest).
//
// Pipeline: buffers t%4. Iter t: vmcnt(8) [tile t landed, t+1/t+2 in flight],
// barrier [all waves' DMA visible], issue 4 gl2lds for tile t+3 into buffer
// (t+3)&3 = (t-1)&3 (consumed last iter, reads ordered before this barrier),
// then ds_read frags + 8 MFMA. One barrier per K-tile, never vmcnt(0).

__global__ __launch_bounds__(256, 2) void gemm_f16_kernel(
    const f16* __restrict__ Xh, const f16* __restrict__ WT,
    const float* __restrict__ bias, float* __restrict__ Y)
{
    __shared__ __align__(16) f16 sA[4][128 * 32];
    __shared__ __align__(16) f16 sB[4][128 * 32];

    const int tid  = threadIdx.x;
    const int wave = tid >> 6;
    const int lane = tid & 63;
    const int half = lane >> 5;   // k-half selector (0/1)
    const int l32  = lane & 31;
    const int wm   = (wave & 1) * 64;
    const int wn   = (wave >> 1) * 64;

    // bijective XCD swizzle: 1536 blocks = 8 XCDs x 192; within an XCD,
    // consecutive blocks sweep cols of a row-panel (A-tile reuse in L2).
    const int bid = blockIdx.x;
    const int swz = (bid & 7) * 192 + (bid >> 3);
    const int bx  = swz % 24;
    const int by  = swz / 24;
    const int row0 = by * 128;
    const int col0 = bx * 128;

    // staging: per K-tile each wave issues 2 A + 2 B gl2lds. One gl2lds writes
    // 1 KB = 16 rows x 64 B, lane -> row g*16+(lane>>2), phys slot lane&3.
    // Source column fetches the logical slot that belongs at that phys slot:
    //   logical = (lane&3) ^ ((lane>>2)&3) ^ ((lane>>4)&3)
    const int lcst = (((lane & 3) ^ ((lane >> 2) & 3) ^ ((lane >> 4) & 3)) * 8);
    const f16* gA[2];
    const f16* gB[2];
    int ldsq[2];
    #pragma unroll
    for (int q = 0; q < 2; ++q) {
        const int g = wave * 2 + q;            // 16-row group 0..7
        gA[q] = Xh + (size_t)(row0 + g * 16 + (lane >> 2)) * GK + lcst;
        gB[q] = WT + (size_t)(col0 + g * 16 + (lane >> 2)) * GK + lcst;
        ldsq[q] = g * 512;                     // halfs: 16 rows * 32
    }

    // fragment LDS offsets: [tile i][ksub], logical slot = ks*2+half
    int offA[2][2], offB[2][2];
    #pragma unroll
    for (int i = 0; i < 2; ++i)
        #pragma unroll
        for (int ks = 0; ks < 2; ++ks) {
            const int rA = wm + i * 32 + l32;
            const int rB = wn + i * 32 + l32;
            const int s  = ks * 2 + half;
            offA[i][ks] = rA * 32 + ((s ^ (rA & 3) ^ ((rA >> 2) & 3)) * 8);
            offB[i][ks] = rB * 32 + ((s ^ (rB & 3) ^ ((rB >> 2) & 3)) * 8);
        }

    f32x16 acc[2][2];
    #pragma unroll
    for (int i = 0; i < 2; ++i)
        #pragma unroll
        for (int j = 0; j < 2; ++j)
            acc[i][j] = (f32x16)0.0f;

    // prologue: stage tiles 0,1,2 (12 loads outstanding per wave)
    #pragma unroll
    for (int tp = 0; tp < 3; ++tp) {
        f16* bA = &sA[tp][0];
        f16* bB = &sB[tp][0];
        const int kk = tp * 32;
        #pragma unroll
        for (int q = 0; q < 2; ++q) {
            gl2lds16(gA[q] + kk, bA + ldsq[q]);
            gl2lds16(gB[q] + kk, bB + ldsq[q]);
        }
    }

    #pragma unroll 4
    for (int t = 0; t < NT; ++t) {
        // own tile-t loads landed (keep 8 = tiles t+1,t+2 in flight) ...
        asm volatile("s_waitcnt vmcnt(8)" ::: "memory");
        // ... then everyone's tile-t loads landed
        __builtin_amdgcn_s_barrier();
        __builtin_amdgcn_sched_barrier(0);

        {   // stage tile t+3 into buffer (t+3)&3 (freed at iter t-1);
            // clamp past the end (re-stages tile 0, never read) to keep the
            // per-wave vmcnt count uniform at 4/tile.
            const int tp = t + 3;
            const int kk = (tp < NT ? tp : 0) * 32;
            f16* bA = &sA[tp & 3][0];
            f16* bB = &sB[tp & 3][0];
            #pragma unroll
            for (int q = 0; q < 2; ++q) {
                gl2lds16(gA[q] + kk, bA + ldsq[q]);
                gl2lds16(gB[q] + kk, bB + ldsq[q]);
            }
        }

        const f16* cA = &sA[t & 3][0];
        const f16* cB = &sB[t & 3][0];
        f16x8 af[2][2], bf[2][2];
        #pragma unroll
        for (int i = 0; i < 2; ++i)
            #pragma unroll
            for (int ks = 0; ks < 2; ++ks) {
                af[i][ks] = *(const f16x8*)(cA + offA[i][ks]);
                bf[i][ks] = *(const f16x8*)(cB + offB[i][ks]);
            }

        __builtin_amdgcn_s_setprio(1);
        #pragma unroll
        for (int ks = 0; ks < 2; ++ks)
            #pragma unroll
            for (int i = 0; i < 2; ++i)
                #pragma unroll
                for (int j = 0; j < 2; ++j)
                    acc[i][j] = __builtin_amdgcn_mfma_f32_32x32x16_f16(
                        af[i][ks], bf[j][ks], acc[i][j], 0, 0, 0);
        __builtin_amdgcn_s_setprio(0);
        // no trailing barrier: next iter's vmcnt+barrier orders the next
        // overwrite after this iter's reads.
    }

    // epilogue: C/D layout col=lane&31, row=(reg&3)+8*(reg>>2)+4*(lane>>5)
    #pragma unroll
    for (int i = 0; i < 2; ++i)
        #pragma unroll
        for (int j = 0; j < 2; ++j) {
            const int c = col0 + wn + j * 32 + l32;
            const float bv = bias[c];
            #pragma unroll
            for (int r = 0; r < 16; ++r) {
                const int rw = row0 + wm + i * 32 + (r & 3) + 8 * (r >> 2) + 4 * half;
                Y[(size_t)rw * GN + c] = acc[i][j][r] + bv;
            }
        }
}

// ---------------- fp32 fallback GEMM (if workspace too small) ----------------

#define BM 128
#define BN 128
#define BK 8
#define TM 8
#define TN 8

__global__ __launch_bounds__(256) void gemm_bias_kernel(
    const float* __restrict__ X, const float* __restrict__ W,
    const float* __restrict__ bias, float* __restrict__ Y)
{
    __shared__ float As[BK][BM];
    __shared__ float Bs[BK][BN];
    const int tid = threadIdx.x;
    const int row0 = blockIdx.y * BM;
    const int col0 = blockIdx.x * BN;
    const int a_row = tid >> 1, a_col4 = (tid & 1) * 4;
    const int b_row = tid >> 5, b_col4 = (tid & 31) * 4;
    const int tx = tid & 15, ty = tid >> 4;
    const float* Xp = X + (size_t)(row0 + a_row) * GK + a_col4;
    const float* Wp = W + (size_t)b_row * GN + (col0 + b_col4);
    float acc[TM][TN];
    #pragma unroll
    for (int i = 0; i < TM; ++i)
        #pragma unroll
        for (int j = 0; j < TN; ++j) acc[i][j] = 0.0f;
    for (int k0 = 0; k0 < GK; k0 += BK) {
        float4 av = *(const float4*)(Xp + k0);
        float4 bv = *(const float4*)(Wp + (size_t)k0 * GN);
        As[a_col4 + 0][a_row] = av.x;
        As[a_col4 + 1][a_row] = av.y;
        As[a_col4 + 2][a_row] = av.z;
        As[a_col4 + 3][a_row] = av.w;
        *(float4*)&Bs[b_row][b_col4] = bv;
        __syncthreads();
        #pragma unroll
        for (int k = 0; k < BK; ++k) {
            float4 a0 = *(const float4*)&As[k][ty * TM];
            float4 a1 = *(const float4*)&As[k][ty * TM + 4];
            float4 b0 = *(const float4*)&Bs[k][tx * TN];
            float4 b1 = *(const float4*)&Bs[k][tx * TN + 4];
            float ar[TM] = {a0.x, a0.y, a0.z, a0.w, a1.x, a1.y, a1.z, a1.w};
            float br[TN] = {b0.x, b0.y, b0.z, b0.w, b1.x, b1.y, b1.z, b1.w};
            #pragma unroll
            for (int i = 0; i < TM; ++i)
                #pragma unroll
                for (int j = 0; j < TN; ++j)
                    acc[i][j] = fmaf(ar[i], br[j], acc[i][j]);
        }
        __syncthreads();
    }
    #pragma unroll
    for (int i = 0; i < TM; ++i) {
        const int gr = row0 + ty * TM + i;
        float* yp = Y + (size_t)gr * GN + col0 + tx * TN;
        #pragma unroll
        for (int j = 0; j < TN; j += 4) {
            float4 v;
            v.x = acc[i][j + 0] + bias[col0 + tx * TN + j + 0];
            v.y = acc[i][j + 1] + bias[col0 + tx * TN + j + 1];
            v.z = acc[i][j + 2] + bias[col0 + tx * TN + j + 2];
            v.w = acc[i][j + 3] + bias[col0 + tx * TN + j + 3];
            *(float4*)(yp + j) = v;
        }
    }
}

// ---------------- FWHT + quantize: 256 thr x 16 elems, register butterflies ----
// 4096 = 16*16*16: three 4-bit register phases; ownership moved by padded-LDS
// transposes (pad p(e)=e+(e>>4) -> all access patterns conflict-free).
// No shuffles; 4 barriers total.

__device__ __forceinline__ int pmap(int e) { return e + (e >> 4); }

__device__ __forceinline__ void bfly16(float v[16]) {
    #pragma unroll
    for (int h = 1; h < 16; h <<= 1)
        #pragma unroll
        for (int g = 0; g < 16; g += 2 * h)
            #pragma unroll
            for (int j = 0; j < h; ++j) {
                const float a = v[g + j], b = v[g + j + h];
                v[g + j] = a + b;
                v[g + j + h] = a - b;
            }
}

__global__ __launch_bounds__(256) void fwht_quant_kernel(float* __restrict__ Y)
{
    __shared__ float s[4096 + 256];
    const int t = threadIdx.x;
    float* yrow = Y + (size_t)blockIdx.x * GN;

    // L1 ownership: e = 16*t + j (bits 0-3 in reg)
    float v[16];
    if (t < 192) {
        #pragma unroll
        for (int q = 0; q < 4; ++q) {
            const float4 a = *(const float4*)(yrow + t * 16 + q * 4);
            v[q * 4 + 0] = a.x; v[q * 4 + 1] = a.y;
            v[q * 4 + 2] = a.z; v[q * 4 + 3] = a.w;
        }
    } else {
        #pragma unroll
        for (int j = 0; j < 16; ++j) v[j] = 0.0f;
    }

    bfly16(v);                                   // bits 0-3

    #pragma unroll
    for (int j = 0; j < 16; ++j) s[pmap(t * 16 + j)] = v[j];
    __syncthreads();
    // L2 ownership: e = (t&15) + 16*j + 256*(t>>4) (bits 4-7 in reg)
    #pragma unroll
    for (int j = 0; j < 16; ++j) v[j] = s[pmap((t & 15) + 16 * j + 256 * (t >> 4))];

    bfly16(v);                                   // bits 4-7

    // write back to own L2 cells (no barrier needed: same cells we just read)
    #pragma unroll
    for (int j = 0; j < 16; ++j) s[pmap((t & 15) + 16 * j + 256 * (t >> 4))] = v[j];
    __syncthreads();
    // L3 ownership: e = t + 256*j (bits 8-11 in reg)
    #pragma unroll
    for (int j = 0; j < 16; ++j) v[j] = s[pmap(t + 256 * j)];

    bfly16(v);                                   // bits 8-11: forward done (unnormalized)

    #pragma unroll
    for (int j = 0; j < 16; ++j) {               // idx = clip(round((v/64)/0.25), -8, 7)
        float idx = rintf(v[j] * 0.0625f);
        idx = fminf(fmaxf(idx, -8.0f), 7.0f);
        v[j] = idx * 0.25f;
    }

    bfly16(v);                                   // inverse bits 8-11

    #pragma unroll
    for (int j = 0; j < 16; ++j) s[pmap(t + 256 * j)] = v[j];
    __syncthreads();
    #pragma unroll
    for (int j = 0; j < 16; ++j) v[j] = s[pmap((t & 15) + 16 * j + 256 * (t >> 4))];

    bfly16(v);                                   // inverse bits 4-7

    #pragma unroll
    for (int j = 0; j < 16; ++j) s[pmap((t & 15) + 16 * j + 256 * (t >> 4))] = v[j];
    __syncthreads();
    #pragma unroll
    for (int j = 0; j < 16; ++j) v[j] = s[pmap(t * 16 + j)];

    bfly16(v);                                   // inverse bits 0-3

    if (t < 192) {
        const float sc = 0.015625f;
        #pragma unroll
        for (int q = 0; q < 4; ++q) {
            float4 a = make_float4(v[q * 4 + 0] * sc, v[q * 4 + 1] * sc,
                                   v[q * 4 + 2] * sc, v[q * 4 + 3] * sc);
            *(float4*)(yrow + t * 16 + q * 4) = a;
        }
    }
}

// ---------------- launch ----------------

extern "C" void kernel_launch(void* const* d_in, const int* in_sizes, int n_in,
                              void* d_out, int out_size, void* d_ws, size_t ws_size,
                              hipStream_t stream) {
    const float* X    = (const float*)d_in[0];   // 8192 x 4096
    const float* W    = (const float*)d_in[1];   // 4096 x 3072
    const float* bias = (const float*)d_in[2];   // 3072
    float* out = (float*)d_out;                  // 8192 x 3072

    const size_t SZ_XH = (size_t)GM * GK * sizeof(f16);  // 64 MB
    const size_t SZ_WT = (size_t)GN * GK * sizeof(f16);  // 24 MB
    const size_t need  = SZ_XH + SZ_WT;                  // 88 MB

    if (ws_size >= need) {
        f16* Xh = (f16*)d_ws;
        f16* WT = (f16*)((char*)d_ws + SZ_XH);

        split_x_kernel<<<(GM * (size_t)GK) / (8 * 256), 256, 0, stream>>>(X, Xh);
        split_wt_kernel<<<dim3(GN / 32, GK / 32), 256, 0, stream>>>(W, WT);
        gemm_f16_kernel<<<(GM / 128) * (GN / 128), 256, 0, stream>>>(Xh, WT, bias, out);
    } else {
        gemm_bias_kernel<<<dim3(GN / BN, GM / BM), 256, 0, stream>>>(X, W, bias, out);
    }

    fwht_quant_kernel<<<GM, 256, 0, stream>>>(out);
}

// Round 2
// 555.812 us; speedup vs baseline: 1.0999x; 1.0999x over previous
//
#include <hip/hip_runtime.h>
#include <hip/hip_bf16.h>
#include <stdint.h>

// y = X(8192x4096) @ W(4096x3072) + b, then rotor quantizer:
// out = fwht(clip(round(fwht(pad(y))/64/0.25),-8,7)*0.25)/64, first 3072 cols.
//
// GEMM: fp16 MFMA 32x32x16, fp32 accumulate.
// R2: 256x256 8-phase-template port. BK=32, quad-buffered LDS (128 KiB,
// 1 block/CU, 8 waves 2Mx4N, per-wave 128x64). Per K-tile: 2 phases, each
// {ds_read subtile || issue 2 gl2lds for tile t+3} -> barrier -> setprio ->
// 8 MFMA -> setprio -> barrier; counted s_waitcnt vmcnt(8) once per K-tile
// (2 tiles = 8 loads stay in flight, never drains to 0). Conflict-free
// 4-slot XOR swizzle (R1: measured 0 bank conflicts) + bijective XCD swizzle.

#define GM 8192
#define GN 3072
#define GK 4096
#define NT 128   // GK / 32 k-tiles

typedef _Float16 f16;
typedef __attribute__((ext_vector_type(8))) _Float16 f16x8;   // 4 VGPRs
typedef __attribute__((ext_vector_type(16))) float f32x16;

__device__ __forceinline__ void gl2lds16(const void* g, void* l) {
    __builtin_amdgcn_global_load_lds(
        (const __attribute__((address_space(1))) void*)g,
        (__attribute__((address_space(3))) void*)l, 16, 0, 0);
}

// ---------------- cast / transpose pre-passes ----------------

struct alignas(16) H8 { f16 v[8]; };

__global__ __launch_bounds__(256) void split_x_kernel(
    const float* __restrict__ X, f16* __restrict__ Xh)
{
    const size_t i = ((size_t)blockIdx.x * 256 + threadIdx.x) * 8;
    const float4 a = *(const float4*)(X + i);
    const float4 b = *(const float4*)(X + i + 4);
    H8 h;
    h.v[0] = (f16)a.x; h.v[1] = (f16)a.y; h.v[2] = (f16)a.z; h.v[3] = (f16)a.w;
    h.v[4] = (f16)b.x; h.v[5] = (f16)b.y; h.v[6] = (f16)b.z; h.v[7] = (f16)b.w;
    *(H8*)(Xh + i) = h;
}

// W: (4096 k) x (3072 n) row-major -> WT: (3072 n) x (4096 k) fp16
__global__ __launch_bounds__(256) void split_wt_kernel(
    const float* __restrict__ W, f16* __restrict__ WT)
{
    __shared__ float tile[32][33];
    const int nt = blockIdx.x * 32;
    const int kt = blockIdx.y * 32;
    const int tx = threadIdx.x & 31;
    const int ty = threadIdx.x >> 5;   // 0..7
    #pragma unroll
    for (int r = 0; r < 4; ++r)
        tile[ty + 8 * r][tx] = W[(size_t)(kt + ty + 8 * r) * GN + nt + tx];
    __syncthreads();
    #pragma unroll
    for (int r = 0; r < 4; ++r)
        WT[(size_t)(nt + ty + 8 * r) * GK + kt + tx] = (f16)tile[tx][ty + 8 * r];
}

// ---------------- fp16 MFMA GEMM, 256x256 tile, BK=32, quad-buffer ----------
// LDS rows: 32 halfs (64 B) = 4 x 16-B slots, phys = s ^ (r&3) ^ ((r>>2)&3)
// (conflict-free on ds_read_b128: R1 measured SQ_LDS_BANK_CONFLICT = 0).
// gl2lds writes linearly; inverse swizzle applied to the GLOBAL source col.
//
// Pipeline: buffers t%4; tiles t+1,t+2 landed-or-in-flight, t+3 being issued.
// Iter t phase 0: ds_read bf(all)+af(rb0,1), issue A-stage of t+3, barrier,
// 8 MFMA, barrier. Phase 1: ds_read af(rb2,3), issue B-stage of t+3, barrier,
// 8 MFMA, vmcnt(8), barrier. The final vmcnt(8)+barrier makes tile t+1 (the
// oldest 4 of the <=12 outstanding loads) visible to all waves.

__global__ __launch_bounds__(512, 2) void gemm_f16_kernel(
    const f16* __restrict__ Xh, const f16* __restrict__ WT,
    const float* __restrict__ bias, float* __restrict__ Y)
{
    __shared__ __align__(16) f16 sA[4][256 * 32];   // 64 KB
    __shared__ __align__(16) f16 sB[4][256 * 32];   // 64 KB

    const int tid  = threadIdx.x;
    const int wave = tid >> 6;     // 0..7
    const int lane = tid & 63;
    const int half = lane >> 5;    // k-half selector (0/1)
    const int l32  = lane & 31;
    const int wr   = wave >> 2;    // 0..1 -> row offset wr*128
    const int wc   = wave & 3;     // 0..3 -> col offset wc*64

    // bijective XCD swizzle: 384 blocks = 8 XCDs x 48; within an XCD,
    // consecutive blocks sweep cols of one 256-row panel (2 MB A in L2).
    const int bid = blockIdx.x;
    const int swz = (bid & 7) * 48 + (bid >> 3);
    const int bx  = swz % 12;
    const int by  = swz / 12;
    const int row0 = by * 256;
    const int col0 = bx * 256;

    // staging: per K-tile each wave issues 2 A + 2 B gl2lds. One gl2lds writes
    // 1 KB = 16 rows x 64 B, lane -> row g*16+(lane>>2), phys slot lane&3.
    // Source col fetches the logical slot belonging at that phys slot:
    //   logical = (lane&3) ^ ((lane>>2)&3) ^ ((lane>>4)&3)
    const int lcst = (((lane & 3) ^ ((lane >> 2) & 3) ^ ((lane >> 4) & 3)) * 8);
    const f16* gA[2];
    const f16* gB[2];
    int ldsq[2];
    #pragma unroll
    for (int q = 0; q < 2; ++q) {
        const int g = wave * 2 + q;            // 16-row group 0..15
        gA[q] = Xh + (size_t)(row0 + g * 16 + (lane >> 2)) * GK + lcst;
        gB[q] = WT + (size_t)(col0 + g * 16 + (lane >> 2)) * GK + lcst;
        ldsq[q] = g * 512;                     // halfs: 16 rows * 32
    }

    // fragment LDS offsets: logical slot = ks*2 + half
    int offA[4][2], offB[2][2];
    #pragma unroll
    for (int rb = 0; rb < 4; ++rb)
        #pragma unroll
        for (int ks = 0; ks < 2; ++ks) {
            const int rA = wr * 128 + rb * 32 + l32;
            const int s  = ks * 2 + half;
            offA[rb][ks] = rA * 32 + ((s ^ (rA & 3) ^ ((rA >> 2) & 3)) * 8);
        }
    #pragma unroll
    for (int cb = 0; cb < 2; ++cb)
        #pragma unroll
        for (int ks = 0; ks < 2; ++ks) {
            const int rB = wc * 64 + cb * 32 + l32;
            const int s  = ks * 2 + half;
            offB[cb][ks] = rB * 32 + ((s ^ (rB & 3) ^ ((rB >> 2) & 3)) * 8);
        }

    f32x16 acc[4][2];
    #pragma unroll
    for (int rb = 0; rb < 4; ++rb)
        #pragma unroll
        for (int cb = 0; cb < 2; ++cb)
            acc[rb][cb] = (f32x16)0.0f;

    // prologue: stage tiles 0,1,2 (12 loads/thread, FIFO order A,A,B,B per tile)
    #pragma unroll
    for (int tp = 0; tp < 3; ++tp) {
        const int kk = tp * 32;
        #pragma unroll
        for (int q = 0; q < 2; ++q) gl2lds16(gA[q] + kk, &sA[tp][ldsq[q]]);
        #pragma unroll
        for (int q = 0; q < 2; ++q) gl2lds16(gB[q] + kk, &sB[tp][ldsq[q]]);
    }
    asm volatile("s_waitcnt vmcnt(8)" ::: "memory");   // tile 0 landed
    __builtin_amdgcn_s_barrier();

    #pragma unroll 4
    for (int t = 0; t < NT; ++t) {
        const f16* cA = &sA[t & 3][0];
        const f16* cB = &sB[t & 3][0];
        // stage target: tile t+3 -> buffer (t+3)&3 = (t-1)&3, whose reads all
        // completed before the barrier that ended iter t-1. Clamp past the end
        // (re-stages tile 0, never read) to keep vmcnt counts uniform.
        const int tp = t + 3;
        const int kk = (tp < NT ? tp : 0) * 32;
        f16* pA = &sA[tp & 3][0];
        f16* pB = &sB[tp & 3][0];

        // ---- phase 0: bf(all) + af(rb0,1); stage A(t+3); 8 MFMA ----
        f16x8 bf[2][2], af[2][2];
        #pragma unroll
        for (int cb = 0; cb < 2; ++cb)
            #pragma unroll
            for (int ks = 0; ks < 2; ++ks)
                bf[cb][ks] = *(const f16x8*)(cB + offB[cb][ks]);
        #pragma unroll
        for (int rb = 0; rb < 2; ++rb)
            #pragma unroll
            for (int ks = 0; ks < 2; ++ks)
                af[rb][ks] = *(const f16x8*)(cA + offA[rb][ks]);
        #pragma unroll
        for (int q = 0; q < 2; ++q) gl2lds16(gA[q] + kk, pA + ldsq[q]);
        __builtin_amdgcn_s_barrier();
        __builtin_amdgcn_s_setprio(1);
        #pragma unroll
        for (int ks = 0; ks < 2; ++ks)
            #pragma unroll
            for (int rb = 0; rb < 2; ++rb)
                #pragma unroll
                for (int cb = 0; cb < 2; ++cb)
                    acc[rb][cb] = __builtin_amdgcn_mfma_f32_32x32x16_f16(
                        af[rb][ks], bf[cb][ks], acc[rb][cb], 0, 0, 0);
        __builtin_amdgcn_s_setprio(0);
        __builtin_amdgcn_s_barrier();

        // ---- phase 1: af(rb2,3); stage B(t+3); 8 MFMA; vmcnt(8) ----
        f16x8 ag[2][2];
        #pragma unroll
        for (int rb = 0; rb < 2; ++rb)
            #pragma unroll
            for (int ks = 0; ks < 2; ++ks)
                ag[rb][ks] = *(const f16x8*)(cA + offA[rb + 2][ks]);
        #pragma unroll
        for (int q = 0; q < 2; ++q) gl2lds16(gB[q] + kk, pB + ldsq[q]);
        __builtin_amdgcn_s_barrier();
        __builtin_amdgcn_s_setprio(1);
        #pragma unroll
        for (int ks = 0; ks < 2; ++ks)
            #pragma unroll
            for (int rb = 0; rb < 2; ++rb)
                #pragma unroll
                for (int cb = 0; cb < 2; ++cb)
                    acc[rb + 2][cb] = __builtin_amdgcn_mfma_f32_32x32x16_f16(
                        ag[rb][ks], bf[cb][ks], acc[rb + 2][cb], 0, 0, 0);
        __builtin_amdgcn_s_setprio(0);
        asm volatile("s_waitcnt vmcnt(8)" ::: "memory");   // tile t+1 landed
        __builtin_amdgcn_s_barrier();
    }

    // epilogue: C/D layout col=lane&31, row=(reg&3)+8*(reg>>2)+4*(lane>>5)
    #pragma unroll
    for (int rb = 0; rb < 4; ++rb)
        #pragma unroll
        for (int cb = 0; cb < 2; ++cb) {
            const int c = col0 + wc * 64 + cb * 32 + l32;
            const float bv = bias[c];
            #pragma unroll
            for (int r = 0; r < 16; ++r) {
                const int rw = row0 + wr * 128 + rb * 32 + (r & 3) + 8 * (r >> 2) + 4 * half;
                Y[(size_t)rw * GN + c] = acc[rb][cb][r] + bv;
            }
        }
}

// ---------------- fp32 fallback GEMM (if workspace too small) ----------------

#define BM 128
#define BN 128
#define BK 8
#define TM 8
#define TN 8

__global__ __launch_bounds__(256) void gemm_bias_kernel(
    const float* __restrict__ X, const float* __restrict__ W,
    const float* __restrict__ bias, float* __restrict__ Y)
{
    __shared__ float As[BK][BM];
    __shared__ float Bs[BK][BN];
    const int tid = threadIdx.x;
    const int row0 = blockIdx.y * BM;
    const int col0 = blockIdx.x * BN;
    const int a_row = tid >> 1, a_col4 = (tid & 1) * 4;
    const int b_row = tid >> 5, b_col4 = (tid & 31) * 4;
    const int tx = tid & 15, ty = tid >> 4;
    const float* Xp = X + (size_t)(row0 + a_row) * GK + a_col4;
    const float* Wp = W + (size_t)b_row * GN + (col0 + b_col4);
    float acc[TM][TN];
    #pragma unroll
    for (int i = 0; i < TM; ++i)
        #pragma unroll
        for (int j = 0; j < TN; ++j) acc[i][j] = 0.0f;
    for (int k0 = 0; k0 < GK; k0 += BK) {
        float4 av = *(const float4*)(Xp + k0);
        float4 bv = *(const float4*)(Wp + (size_t)k0 * GN);
        As[a_col4 + 0][a_row] = av.x;
        As[a_col4 + 1][a_row] = av.y;
        As[a_col4 + 2][a_row] = av.z;
        As[a_col4 + 3][a_row] = av.w;
        *(float4*)&Bs[b_row][b_col4] = bv;
        __syncthreads();
        #pragma unroll
        for (int k = 0; k < BK; ++k) {
            float4 a0 = *(const float4*)&As[k][ty * TM];
            float4 a1 = *(const float4*)&As[k][ty * TM + 4];
            float4 b0 = *(const float4*)&Bs[k][tx * TN];
            float4 b1 = *(const float4*)&Bs[k][tx * TN + 4];
            float ar[TM] = {a0.x, a0.y, a0.z, a0.w, a1.x, a1.y, a1.z, a1.w};
            float br[TN] = {b0.x, b0.y, b0.z, b0.w, b1.x, b1.y, b1.z, b1.w};
            #pragma unroll
            for (int i = 0; i < TM; ++i)
                #pragma unroll
                for (int j = 0; j < TN; ++j)
                    acc[i][j] = fmaf(ar[i], br[j], acc[i][j]);
        }
        __syncthreads();
    }
    #pragma unroll
    for (int i = 0; i < TM; ++i) {
        const int gr = row0 + ty * TM + i;
        float* yp = Y + (size_t)gr * GN + col0 + tx * TN;
        #pragma unroll
        for (int j = 0; j < TN; j += 4) {
            float4 v;
            v.x = acc[i][j + 0] + bias[col0 + tx * TN + j + 0];
            v.y = acc[i][j + 1] + bias[col0 + tx * TN + j + 1];
            v.z = acc[i][j + 2] + bias[col0 + tx * TN + j + 2];
            v.w = acc[i][j + 3] + bias[col0 + tx * TN + j + 3];
            *(float4*)(yp + j) = v;
        }
    }
}

// ---------------- FWHT + quantize: 256 thr x 16 elems, register butterflies ----
// 4096 = 16*16*16: three 4-bit register phases; ownership moved by padded-LDS
// transposes (pad p(e)=e+(e>>4) -> all access patterns conflict-free).
// No shuffles; 4 barriers total.

__device__ __forceinline__ int pmap(int e) { return e + (e >> 4); }

__device__ __forceinline__ void bfly16(float v[16]) {
    #pragma unroll
    for (int h = 1; h < 16; h <<= 1)
        #pragma unroll
        for (int g = 0; g < 16; g += 2 * h)
            #pragma unroll
            for (int j = 0; j < h; ++j) {
                const float a = v[g + j], b = v[g + j + h];
                v[g + j] = a + b;
                v[g + j + h] = a - b;
            }
}

__global__ __launch_bounds__(256) void fwht_quant_kernel(float* __restrict__ Y)
{
    __shared__ float s[4096 + 256];
    const int t = threadIdx.x;
    float* yrow = Y + (size_t)blockIdx.x * GN;

    // L1 ownership: e = 16*t + j (bits 0-3 in reg)
    float v[16];
    if (t < 192) {
        #pragma unroll
        for (int q = 0; q < 4; ++q) {
            const float4 a = *(const float4*)(yrow + t * 16 + q * 4);
            v[q * 4 + 0] = a.x; v[q * 4 + 1] = a.y;
            v[q * 4 + 2] = a.z; v[q * 4 + 3] = a.w;
        }
    } else {
        #pragma unroll
        for (int j = 0; j < 16; ++j) v[j] = 0.0f;
    }

    bfly16(v);                                   // bits 0-3

    #pragma unroll
    for (int j = 0; j < 16; ++j) s[pmap(t * 16 + j)] = v[j];
    __syncthreads();
    // L2 ownership: e = (t&15) + 16*j + 256*(t>>4) (bits 4-7 in reg)
    #pragma unroll
    for (int j = 0; j < 16; ++j) v[j] = s[pmap((t & 15) + 16 * j + 256 * (t >> 4))];

    bfly16(v);                                   // bits 4-7

    // write back to own L2 cells (no barrier needed: same cells we just read)
    #pragma unroll
    for (int j = 0; j < 16; ++j) s[pmap((t & 15) + 16 * j + 256 * (t >> 4))] = v[j];
    __syncthreads();
    // L3 ownership: e = t + 256*j (bits 8-11 in reg)
    #pragma unroll
    for (int j = 0; j < 16; ++j) v[j] = s[pmap(t + 256 * j)];

    bfly16(v);                                   // bits 8-11: forward done (unnormalized)

    #pragma unroll
    for (int j = 0; j < 16; ++j) {               // idx = clip(round((v/64)/0.25), -8, 7)
        float idx = rintf(v[j] * 0.0625f);
        idx = fminf(fmaxf(idx, -8.0f), 7.0f);
        v[j] = idx * 0.25f;
    }

    bfly16(v);                                   // inverse bits 8-11

    #pragma unroll
    for (int j = 0; j < 16; ++j) s[pmap(t + 256 * j)] = v[j];
    __syncthreads();
    #pragma unroll
    for (int j = 0; j < 16; ++j) v[j] = s[pmap((t & 15) + 16 * j + 256 * (t >> 4))];

    bfly16(v);                                   // inverse bits 4-7

    #pragma unroll
    for (int j = 0; j < 16; ++j) s[pmap((t & 15) + 16 * j + 256 * (t >> 4))] = v[j];
    __syncthreads();
    #pragma unroll
    for (int j = 0; j < 16; ++j) v[j] = s[pmap(t * 16 + j)];

    bfly16(v);                                   // inverse bits 0-3

    if (t < 192) {
        const float sc = 0.015625f;
        #pragma unroll
        for (int q = 0; q < 4; ++q) {
            float4 a = make_float4(v[q * 4 + 0] * sc, v[q * 4 + 1] * sc,
                                   v[q * 4 + 2] * sc, v[q * 4 + 3] * sc);
            *(float4*)(yrow + t * 16 + q * 4) = a;
        }
    }
}

// ---------------- launch ----------------

extern "C" void kernel_launch(void* const* d_in, const int* in_sizes, int n_in,
                              void* d_out, int out_size, void* d_ws, size_t ws_size,
                              hipStream_t stream) {
    const float* X    = (const float*)d_in[0];   // 8192 x 4096
    const float* W    = (const float*)d_in[1];   // 4096 x 3072
    const float* bias = (const float*)d_in[2];   // 3072
    float* out = (float*)d_out;                  // 8192 x 3072

    const size_t SZ_XH = (size_t)GM * GK * sizeof(f16);  // 64 MB
    const size_t SZ_WT = (size_t)GN * GK * sizeof(f16);  // 24 MB
    const size_t need  = SZ_XH + SZ_WT;                  // 88 MB

    if (ws_size >= need) {
        f16* Xh = (f16*)d_ws;
        f16* WT = (f16*)((char*)d_ws + SZ_XH);

        split_x_kernel<<<(GM * (size_t)GK) / (8 * 256), 256, 0, stream>>>(X, Xh);
        split_wt_kernel<<<dim3(GN / 32, GK / 32), 256, 0, stream>>>(W, WT);
        gemm_f16_kernel<<<(GM / 256) * (GN / 256), 512, 0, stream>>>(Xh, WT, bias, out);
    } else {
        gemm_bias_kernel<<<dim3(GN / BN, GM / BM), 256, 0, stream>>>(X, W, bias, out);
    }

    fwht_quant_kernel<<<GM, 256, 0, stream>>>(out);
}

// Round 3
// 544.061 us; speedup vs baseline: 1.1237x; 1.0216x over previous
//
#include <hip/hip_runtime.h>
#include <hip/hip_bf16.h>
#include <stdint.h>

// y = X(8192x4096) @ W(4096x3072) + b, then rotor quantizer:
// out = fwht(clip(round(fwht(pad(y))/64/0.25),-8,7)*0.25)/64, first 3072 cols.
//
// GEMM: fp16 MFMA 32x32x16, fp32 accumulate.
// R3: 128x128 tile (1536 blocks = 6/CU exact, no tail), BK=32, TRIPLE-buffered
// LDS (48 KiB -> 3 blocks/CU co-resident, R0's cross-block overlap) + counted
// s_waitcnt vmcnt(4) never drained to 0 (T4, removes the barrier-drain stall)
// + R2's two-barrier phase + setprio + R1's measured-conflict-free 4-slot
// swizzle + bijective XCD swizzle. Layouts identical to R1/R2 (verified).

#define GM 8192
#define GN 3072
#define GK 4096
#define NT 128   // GK / 32 k-tiles
#define BUFH 8192   // halfs per buffer: A 128x32 + B 128x32

typedef _Float16 f16;
typedef __attribute__((ext_vector_type(8))) _Float16 f16x8;   // 4 VGPRs
typedef __attribute__((ext_vector_type(16))) float f32x16;

__device__ __forceinline__ void gl2lds16(const void* g, void* l) {
    __builtin_amdgcn_global_load_lds(
        (const __attribute__((address_space(1))) void*)g,
        (__attribute__((address_space(3))) void*)l, 16, 0, 0);
}

// ---------------- cast / transpose pre-passes ----------------

struct alignas(16) H8 { f16 v[8]; };

__global__ __launch_bounds__(256) void split_x_kernel(
    const float* __restrict__ X, f16* __restrict__ Xh)
{
    const size_t i = ((size_t)blockIdx.x * 256 + threadIdx.x) * 8;
    const float4 a = *(const float4*)(X + i);
    const float4 b = *(const float4*)(X + i + 4);
    H8 h;
    h.v[0] = (f16)a.x; h.v[1] = (f16)a.y; h.v[2] = (f16)a.z; h.v[3] = (f16)a.w;
    h.v[4] = (f16)b.x; h.v[5] = (f16)b.y; h.v[6] = (f16)b.z; h.v[7] = (f16)b.w;
    *(H8*)(Xh + i) = h;
}

// W: (4096 k) x (3072 n) row-major -> WT: (3072 n) x (4096 k) fp16
__global__ __launch_bounds__(256) void split_wt_kernel(
    const float* __restrict__ W, f16* __restrict__ WT)
{
    __shared__ float tile[32][33];
    const int nt = blockIdx.x * 32;
    const int kt = blockIdx.y * 32;
    const int tx = threadIdx.x & 31;
    const int ty = threadIdx.x >> 5;   // 0..7
    #pragma unroll
    for (int r = 0; r < 4; ++r)
        tile[ty + 8 * r][tx] = W[(size_t)(kt + ty + 8 * r) * GN + nt + tx];
    __syncthreads();
    #pragma unroll
    for (int r = 0; r < 4; ++r)
        WT[(size_t)(nt + ty + 8 * r) * GK + kt + tx] = (f16)tile[tx][ty + 8 * r];
}

// ---------------- fp16 MFMA GEMM, 128x128 tile, BK=32, triple-buffer --------
// LDS rows: 32 halfs (64 B) = 4 x 16-B slots, phys = s ^ (r&3) ^ ((r>>2)&3)
// (R1/R2: measured SQ_LDS_BANK_CONFLICT = 0). gl2lds writes linearly; the
// inverse swizzle is applied to the GLOBAL source column.
//
// Pipeline (3 bufs, t%3): iter t reads buf cur (tile t), stages tile t+2 into
// buf fut (= buf of t-1, whose reads completed before the barrier that ended
// iter t-1: every wave's ds_reads drain (lgkmcnt) before its MFMAs, which
// precede that barrier). Phase: {ds_read 8xb128; issue 4 gl2lds; barrier;
// setprio; 8 MFMA; setprio; vmcnt(4) [tile t+1 landed, t+2 in flight];
// barrier}. vmcnt never drains to 0 in the loop.

__global__ __launch_bounds__(256) void gemm_f16_kernel(
    const f16* __restrict__ Xh, const f16* __restrict__ WT,
    const float* __restrict__ bias, float* __restrict__ Y)
{
    __shared__ __align__(16) f16 smem[3 * BUFH];   // 48 KB

    const int tid  = threadIdx.x;
    const int wave = tid >> 6;     // 0..3
    const int lane = tid & 63;
    const int half = lane >> 5;    // k-half selector (0/1)
    const int l32  = lane & 31;
    const int wm   = (wave & 1) * 64;
    const int wn   = (wave >> 1) * 64;

    // bijective XCD swizzle: 1536 blocks = 8 XCDs x 192; within an XCD,
    // 24 consecutive blocks sweep the cols of one 128-row panel (1 MB A in L2).
    const int bid = blockIdx.x;
    const int swz = (bid & 7) * 192 + (bid >> 3);
    const int bx  = swz % 24;
    const int by  = swz / 24;
    const int row0 = by * 128;
    const int col0 = bx * 128;

    // staging: per K-tile each wave issues 2 A + 2 B gl2lds. One gl2lds writes
    // 1 KB = 16 rows x 64 B, lane -> row base+(lane>>2), phys slot lane&3.
    // Source col fetches the logical slot belonging at that phys slot:
    //   logical = (lane&3) ^ ((lane>>2)&3) ^ ((lane>>4)&3)
    const int lcst = (((lane & 3) ^ ((lane >> 2) & 3) ^ ((lane >> 4) & 3)) * 8);
    const f16* gA[2];
    const f16* gB[2];
    int ldsq[2];
    #pragma unroll
    for (int q = 0; q < 2; ++q) {
        const int r0 = wave * 32 + q * 16;     // 16-row group base
        gA[q] = Xh + (size_t)(row0 + r0 + (lane >> 2)) * GK + lcst;
        gB[q] = WT + (size_t)(col0 + r0 + (lane >> 2)) * GK + lcst;
        ldsq[q] = r0 * 32;                     // halfs
    }

    // fragment LDS offsets: logical slot = ks*2 + half
    int offA[2][2], offB[2][2];
    #pragma unroll
    for (int i = 0; i < 2; ++i)
        #pragma unroll
        for (int ks = 0; ks < 2; ++ks) {
            const int rA = wm + i * 32 + l32;
            const int rB = wn + i * 32 + l32;
            const int s  = ks * 2 + half;
            offA[i][ks] = rA * 32 + ((s ^ (rA & 3) ^ ((rA >> 2) & 3)) * 8);
            offB[i][ks] = rB * 32 + ((s ^ (rB & 3) ^ ((rB >> 2) & 3)) * 8);
        }

    f32x16 acc[2][2];
    #pragma unroll
    for (int i = 0; i < 2; ++i)
        #pragma unroll
        for (int j = 0; j < 2; ++j)
            acc[i][j] = (f32x16)0.0f;

    // prologue: stage tiles 0 (buf 0) and 1 (buf 1); FIFO A,A,B,B per tile.
    #pragma unroll
    for (int tp = 0; tp < 2; ++tp) {
        const int kk = tp * 32;
        f16* bA = &smem[tp * BUFH];
        f16* bB = bA + 4096;
        #pragma unroll
        for (int q = 0; q < 2; ++q) gl2lds16(gA[q] + kk, bA + ldsq[q]);
        #pragma unroll
        for (int q = 0; q < 2; ++q) gl2lds16(gB[q] + kk, bB + ldsq[q]);
    }
    asm volatile("s_waitcnt vmcnt(4)" ::: "memory");   // tile 0 landed
    __builtin_amdgcn_s_barrier();

    int cur = 0, nxt = BUFH, fut = 2 * BUFH;   // half-offsets of bufs t,t+1,t+2

    #pragma unroll 3
    for (int t = 0; t < NT; ++t) {
        const f16* cA = &smem[cur];
        const f16* cB = cA + 4096;

        // ds_read this tile's fragments
        f16x8 af[2][2], bf[2][2];
        #pragma unroll
        for (int i = 0; i < 2; ++i)
            #pragma unroll
            for (int ks = 0; ks < 2; ++ks) {
                af[i][ks] = *(const f16x8*)(cA + offA[i][ks]);
                bf[i][ks] = *(const f16x8*)(cB + offB[i][ks]);
            }

        // stage tile t+2 into buf fut (freed after iter t-1). Clamp past the
        // end (re-stages tile 0 into a never-again-read buffer) to keep the
        // per-wave vmcnt count uniform at 4/tile.
        {
            const int tp = t + 2;
            const int kk = (tp < NT ? tp : 0) * 32;
            f16* pA = &smem[fut];
            f16* pB = pA + 4096;
            #pragma unroll
            for (int q = 0; q < 2; ++q) gl2lds16(gA[q] + kk, pA + ldsq[q]);
            #pragma unroll
            for (int q = 0; q < 2; ++q) gl2lds16(gB[q] + kk, pB + ldsq[q]);
        }

        __builtin_amdgcn_s_barrier();
        __builtin_amdgcn_s_setprio(1);
        #pragma unroll
        for (int ks = 0; ks < 2; ++ks)
            #pragma unroll
            for (int i = 0; i < 2; ++i)
                #pragma unroll
                for (int j = 0; j < 2; ++j)
                    acc[i][j] = __builtin_amdgcn_mfma_f32_32x32x16_f16(
                        af[i][ks], bf[j][ks], acc[i][j], 0, 0, 0);
        __builtin_amdgcn_s_setprio(0);
        asm volatile("s_waitcnt vmcnt(4)" ::: "memory");   // tile t+1 landed
        __builtin_amdgcn_s_barrier();

        const int tmp = cur; cur = nxt; nxt = fut; fut = tmp;
    }

    // epilogue: C/D layout col=lane&31, row=(reg&3)+8*(reg>>2)+4*(lane>>5)
    #pragma unroll
    for (int i = 0; i < 2; ++i)
        #pragma unroll
        for (int j = 0; j < 2; ++j) {
            const int c = col0 + wn + j * 32 + l32;
            const float bv = bias[c];
            #pragma unroll
            for (int r = 0; r < 16; ++r) {
                const int rw = row0 + wm + i * 32 + (r & 3) + 8 * (r >> 2) + 4 * half;
                Y[(size_t)rw * GN + c] = acc[i][j][r] + bv;
            }
        }
}

// ---------------- fp32 fallback GEMM (if workspace too small) ----------------

#define BM 128
#define BN 128
#define BK 8
#define TM 8
#define TN 8

__global__ __launch_bounds__(256) void gemm_bias_kernel(
    const float* __restrict__ X, const float* __restrict__ W,
    const float* __restrict__ bias, float* __restrict__ Y)
{
    __shared__ float As[BK][BM];
    __shared__ float Bs[BK][BN];
    const int tid = threadIdx.x;
    const int row0 = blockIdx.y * BM;
    const int col0 = blockIdx.x * BN;
    const int a_row = tid >> 1, a_col4 = (tid & 1) * 4;
    const int b_row = tid >> 5, b_col4 = (tid & 31) * 4;
    const int tx = tid & 15, ty = tid >> 4;
    const float* Xp = X + (size_t)(row0 + a_row) * GK + a_col4;
    const float* Wp = W + (size_t)b_row * GN + (col0 + b_col4);
    float acc[TM][TN];
    #pragma unroll
    for (int i = 0; i < TM; ++i)
        #pragma unroll
        for (int j = 0; j < TN; ++j) acc[i][j] = 0.0f;
    for (int k0 = 0; k0 < GK; k0 += BK) {
        float4 av = *(const float4*)(Xp + k0);
        float4 bv = *(const float4*)(Wp + (size_t)k0 * GN);
        As[a_col4 + 0][a_row] = av.x;
        As[a_col4 + 1][a_row] = av.y;
        As[a_col4 + 2][a_row] = av.z;
        As[a_col4 + 3][a_row] = av.w;
        *(float4*)&Bs[b_row][b_col4] = bv;
        __syncthreads();
        #pragma unroll
        for (int k = 0; k < BK; ++k) {
            float4 a0 = *(const float4*)&As[k][ty * TM];
            float4 a1 = *(const float4*)&As[k][ty * TM + 4];
            float4 b0 = *(const float4*)&Bs[k][tx * TN];
            float4 b1 = *(const float4*)&Bs[k][tx * TN + 4];
            float ar[TM] = {a0.x, a0.y, a0.z, a0.w, a1.x, a1.y, a1.z, a1.w};
            float br[TN] = {b0.x, b0.y, b0.z, b0.w, b1.x, b1.y, b1.z, b1.w};
            #pragma unroll
            for (int i = 0; i < TM; ++i)
                #pragma unroll
                for (int j = 0; j < TN; ++j)
                    acc[i][j] = fmaf(ar[i], br[j], acc[i][j]);
        }
        __syncthreads();
    }
    #pragma unroll
    for (int i = 0; i < TM; ++i) {
        const int gr = row0 + ty * TM + i;
        float* yp = Y + (size_t)gr * GN + col0 + tx * TN;
        #pragma unroll
        for (int j = 0; j < TN; j += 4) {
            float4 v;
            v.x = acc[i][j + 0] + bias[col0 + tx * TN + j + 0];
            v.y = acc[i][j + 1] + bias[col0 + tx * TN + j + 1];
            v.z = acc[i][j + 2] + bias[col0 + tx * TN + j + 2];
            v.w = acc[i][j + 3] + bias[col0 + tx * TN + j + 3];
            *(float4*)(yp + j) = v;
        }
    }
}

// ---------------- FWHT + quantize: 256 thr x 16 elems, register butterflies ----
// 4096 = 16*16*16: three 4-bit register phases; ownership moved by padded-LDS
// transposes (pad p(e)=e+(e>>4) -> all access patterns conflict-free).
// No shuffles; 4 barriers total.

__device__ __forceinline__ int pmap(int e) { return e + (e >> 4); }

__device__ __forceinline__ void bfly16(float v[16]) {
    #pragma unroll
    for (int h = 1; h < 16; h <<= 1)
        #pragma unroll
        for (int g = 0; g < 16; g += 2 * h)
            #pragma unroll
            for (int j = 0; j < h; ++j) {
                const float a = v[g + j], b = v[g + j + h];
                v[g + j] = a + b;
                v[g + j + h] = a - b;
            }
}

__global__ __launch_bounds__(256) void fwht_quant_kernel(float* __restrict__ Y)
{
    __shared__ float s[4096 + 256];
    const int t = threadIdx.x;
    float* yrow = Y + (size_t)blockIdx.x * GN;

    // L1 ownership: e = 16*t + j (bits 0-3 in reg)
    float v[16];
    if (t < 192) {
        #pragma unroll
        for (int q = 0; q < 4; ++q) {
            const float4 a = *(const float4*)(yrow + t * 16 + q * 4);
            v[q * 4 + 0] = a.x; v[q * 4 + 1] = a.y;
            v[q * 4 + 2] = a.z; v[q * 4 + 3] = a.w;
        }
    } else {
        #pragma unroll
        for (int j = 0; j < 16; ++j) v[j] = 0.0f;
    }

    bfly16(v);                                   // bits 0-3

    #pragma unroll
    for (int j = 0; j < 16; ++j) s[pmap(t * 16 + j)] = v[j];
    __syncthreads();
    // L2 ownership: e = (t&15) + 16*j + 256*(t>>4) (bits 4-7 in reg)
    #pragma unroll
    for (int j = 0; j < 16; ++j) v[j] = s[pmap((t & 15) + 16 * j + 256 * (t >> 4))];

    bfly16(v);                                   // bits 4-7

    // write back to own L2 cells (no barrier needed: same cells we just read)
    #pragma unroll
    for (int j = 0; j < 16; ++j) s[pmap((t & 15) + 16 * j + 256 * (t >> 4))] = v[j];
    __syncthreads();
    // L3 ownership: e = t + 256*j (bits 8-11 in reg)
    #pragma unroll
    for (int j = 0; j < 16; ++j) v[j] = s[pmap(t + 256 * j)];

    bfly16(v);                                   // bits 8-11: forward done (unnormalized)

    #pragma unroll
    for (int j = 0; j < 16; ++j) {               // idx = clip(round((v/64)/0.25), -8, 7)
        float idx = rintf(v[j] * 0.0625f);
        idx = fminf(fmaxf(idx, -8.0f), 7.0f);
        v[j] = idx * 0.25f;
    }

    bfly16(v);                                   // inverse bits 8-11

    #pragma unroll
    for (int j = 0; j < 16; ++j) s[pmap(t + 256 * j)] = v[j];
    __syncthreads();
    #pragma unroll
    for (int j = 0; j < 16; ++j) v[j] = s[pmap((t & 15) + 16 * j + 256 * (t >> 4))];

    bfly16(v);                                   // inverse bits 4-7

    #pragma unroll
    for (int j = 0; j < 16; ++j) s[pmap((t & 15) + 16 * j + 256 * (t >> 4))] = v[j];
    __syncthreads();
    #pragma unroll
    for (int j = 0; j < 16; ++j) v[j] = s[pmap(t * 16 + j)];

    bfly16(v);                                   // inverse bits 0-3

    if (t < 192) {
        const float sc = 0.015625f;
        #pragma unroll
        for (int q = 0; q < 4; ++q) {
            float4 a = make_float4(v[q * 4 + 0] * sc, v[q * 4 + 1] * sc,
                                   v[q * 4 + 2] * sc, v[q * 4 + 3] * sc);
            *(float4*)(yrow + t * 16 + q * 4) = a;
        }
    }
}

// ---------------- launch ----------------

extern "C" void kernel_launch(void* const* d_in, const int* in_sizes, int n_in,
                              void* d_out, int out_size, void* d_ws, size_t ws_size,
                              hipStream_t stream) {
    const float* X    = (const float*)d_in[0];   // 8192 x 4096
    const float* W    = (const float*)d_in[1];   // 4096 x 3072
    const float* bias = (const float*)d_in[2];   // 3072
    float* out = (float*)d_out;                  // 8192 x 3072

    const size_t SZ_XH = (size_t)GM * GK * sizeof(f16);  // 64 MB
    const size_t SZ_WT = (size_t)GN * GK * sizeof(f16);  // 24 MB
    const size_t need  = SZ_XH + SZ_WT;                  // 88 MB

    if (ws_size >= need) {
        f16* Xh = (f16*)d_ws;
        f16* WT = (f16*)((char*)d_ws + SZ_XH);

        split_x_kernel<<<(GM * (size_t)GK) / (8 * 256), 256, 0, stream>>>(X, Xh);
        split_wt_kernel<<<dim3(GN / 32, GK / 32), 256, 0, stream>>>(W, WT);
        gemm_f16_kernel<<<(GM / 128) * (GN / 128), 256, 0, stream>>>(Xh, WT, bias, out);
    } else {
        gemm_bias_kernel<<<dim3(GN / BN, GM / BM), 256, 0, stream>>>(X, W, bias, out);
    }

    fwht_quant_kernel<<<GM, 256, 0, stream>>>(out);
}

// Round 4
// 522.201 us; speedup vs baseline: 1.1707x; 1.0419x over previous
//
#include <hip/hip_runtime.h>
#include <hip/hip_bf16.h>
#include <stdint.h>

// y = X(8192x4096) @ W(4096x3072) + b, then rotor quantizer:
// out = fwht(clip(round(fwht(pad(y))/64/0.25),-8,7)*0.25)/64, first 3072 cols.
//
// GEMM: single fp16 MFMA (32x32x16), fp32 accumulate. fp16 roundoff gives
// y-error std ~4e-4 -> ~5 quant-level flips/row -> absmax ~0.06 < 0.11 thr.
//
// R4: GEMM reverted to the R0 structure (m97-family, 128x128, BK=64,
// compiler-scheduled drain) - measured 230 us / 43% MfmaUtil; all three
// hand-pipelined variants (R1-R3) regressed. fwht_quant now processes
// TWO rows per block (same barriers serve both rows) to halve the
// barrier+launch overhead of the quantizer pass.

#define GM 8192
#define GN 3072
#define GK 4096

typedef _Float16 f16;
typedef __attribute__((ext_vector_type(8))) _Float16 f16x8;   // 4 VGPRs
typedef __attribute__((ext_vector_type(16))) float f32x16;

__device__ __forceinline__ void gl2lds16(const void* g, void* l) {
    __builtin_amdgcn_global_load_lds(
        (const __attribute__((address_space(1))) void*)g,
        (__attribute__((address_space(3))) void*)l, 16, 0, 0);
}

// ---------------- cast / transpose pre-passes ----------------

struct alignas(16) H8 { f16 v[8]; };

__global__ __launch_bounds__(256) void split_x_kernel(
    const float* __restrict__ X, f16* __restrict__ Xh)
{
    const size_t i = ((size_t)blockIdx.x * 256 + threadIdx.x) * 8;
    const float4 a = *(const float4*)(X + i);
    const float4 b = *(const float4*)(X + i + 4);
    H8 h;
    h.v[0] = (f16)a.x; h.v[1] = (f16)a.y; h.v[2] = (f16)a.z; h.v[3] = (f16)a.w;
    h.v[4] = (f16)b.x; h.v[5] = (f16)b.y; h.v[6] = (f16)b.z; h.v[7] = (f16)b.w;
    *(H8*)(Xh + i) = h;
}

// W: (4096 k) x (3072 n) row-major -> WT: (3072 n) x (4096 k) fp16
__global__ __launch_bounds__(256) void split_wt_kernel(
    const float* __restrict__ W, f16* __restrict__ WT)
{
    __shared__ float tile[32][33];
    const int nt = blockIdx.x * 32;
    const int kt = blockIdx.y * 32;
    const int tx = threadIdx.x & 31;
    const int ty = threadIdx.x >> 5;   // 0..7
    #pragma unroll
    for (int r = 0; r < 4; ++r)
        tile[ty + 8 * r][tx] = W[(size_t)(kt + ty + 8 * r) * GN + nt + tx];
    __syncthreads();
    #pragma unroll
    for (int r = 0; r < 4; ++r)
        WT[(size_t)(nt + ty + 8 * r) * GK + kt + tx] = (f16)tile[tx][ty + 8 * r];
}

// ---------------- fp16 MFMA GEMM (32x32x16), 128x128 tile, BK=64 ----------------
// (R0 structure, verified 230 us / MfmaUtil 43%.)
// LDS rows: 64 halfs (128 B) = 8 x 16-B slots, XOR-swizzled: phys = s ^ (row&7).
// 4 waves (2x2), each wave 64x64 as 2x2 of 32x32 accs, 16 MFMA per barrier.

__global__ __launch_bounds__(256) void gemm_f16_kernel(
    const f16* __restrict__ Xh, const f16* __restrict__ WT,
    const float* __restrict__ bias, float* __restrict__ Y)
{
    __shared__ __align__(16) f16 sA[128 * 64];
    __shared__ __align__(16) f16 sB[128 * 64];

    const int tid  = threadIdx.x;
    const int wave = tid >> 6;
    const int lane = tid & 63;
    const int half = lane >> 5;   // k-half selector (0/1)
    const int l32  = lane & 31;
    const int wm   = (wave & 1) * 64;
    const int wn   = (wave >> 1) * 64;

    const int row0 = blockIdx.y * 128;
    const int col0 = blockIdx.x * 128;

    // staging: each gl2lds16 instr writes 8 rows (64 lanes x 16B = 1 KB).
    // lane -> row base+ (lane>>3), phys slot lane&7; logical slot = (l&7)^((l>>3)&7).
    const int lr8 = lane >> 3;                              // 0..7
    const int lc  = ((lane & 7) ^ ((lane >> 3) & 7)) * 8;   // global col (halfs)

    const f16* gA[4];
    const f16* gB[4];
    f16* dA[4];
    f16* dB[4];
    #pragma unroll
    for (int q = 0; q < 4; ++q) {
        const int g = wave * 4 + q;        // 8-row group index 0..15
        gA[q] = Xh + (size_t)(row0 + g * 8 + lr8) * GK + lc;
        gB[q] = WT + (size_t)(col0 + g * 8 + lr8) * GK + lc;
        dA[q] = &sA[g * 512];
        dB[q] = &sB[g * 512];
    }

    // fragment LDS offsets: [tile i][ksub 0..3]
    int offA[2][4], offB[2][4];
    #pragma unroll
    for (int i = 0; i < 2; ++i)
        #pragma unroll
        for (int ks = 0; ks < 4; ++ks) {
            const int rA = wm + i * 32 + l32;
            const int rB = wn + i * 32 + l32;
            offA[i][ks] = rA * 64 + (((ks * 2 + half) ^ (rA & 7)) * 8);
            offB[i][ks] = rB * 64 + (((ks * 2 + half) ^ (rB & 7)) * 8);
        }

    f32x16 acc[2][2];
    #pragma unroll
    for (int i = 0; i < 2; ++i)
        #pragma unroll
        for (int j = 0; j < 2; ++j)
            acc[i][j] = (f32x16)0.0f;

    for (int k0 = 0; k0 < GK; k0 += 64) {
        #pragma unroll
        for (int q = 0; q < 4; ++q) {
            gl2lds16(gA[q] + k0, dA[q]);
            gl2lds16(gB[q] + k0, dB[q]);
        }
        __syncthreads();

        f16x8 af[2][4], bf[2][4];
        #pragma unroll
        for (int i = 0; i < 2; ++i)
            #pragma unroll
            for (int ks = 0; ks < 4; ++ks) {
                af[i][ks] = *(const f16x8*)&sA[offA[i][ks]];
                bf[i][ks] = *(const f16x8*)&sB[offB[i][ks]];
            }
        #pragma unroll
        for (int ks = 0; ks < 4; ++ks)
            #pragma unroll
            for (int i = 0; i < 2; ++i)
                #pragma unroll
                for (int j = 0; j < 2; ++j)
                    acc[i][j] = __builtin_amdgcn_mfma_f32_32x32x16_f16(af[i][ks], bf[j][ks], acc[i][j], 0, 0, 0);
        __syncthreads();
    }

    // epilogue: C/D layout col=lane&31, row=(reg&3)+8*(reg>>2)+4*(lane>>5)
    #pragma unroll
    for (int i = 0; i < 2; ++i)
        #pragma unroll
        for (int j = 0; j < 2; ++j) {
            const int c = col0 + wn + j * 32 + l32;
            const float bv = bias[c];
            #pragma unroll
            for (int r = 0; r < 16; ++r) {
                const int rw = row0 + wm + i * 32 + (r & 3) + 8 * (r >> 2) + 4 * half;
                Y[(size_t)rw * GN + c] = acc[i][j][r] + bv;
            }
        }
}

// ---------------- fp32 fallback GEMM (if workspace too small) ----------------

#define BM 128
#define BN 128
#define BK 8
#define TM 8
#define TN 8

__global__ __launch_bounds__(256) void gemm_bias_kernel(
    const float* __restrict__ X, const float* __restrict__ W,
    const float* __restrict__ bias, float* __restrict__ Y)
{
    __shared__ float As[BK][BM];
    __shared__ float Bs[BK][BN];
    const int tid = threadIdx.x;
    const int row0 = blockIdx.y * BM;
    const int col0 = blockIdx.x * BN;
    const int a_row = tid >> 1, a_col4 = (tid & 1) * 4;
    const int b_row = tid >> 5, b_col4 = (tid & 31) * 4;
    const int tx = tid & 15, ty = tid >> 4;
    const float* Xp = X + (size_t)(row0 + a_row) * GK + a_col4;
    const float* Wp = W + (size_t)b_row * GN + (col0 + b_col4);
    float acc[TM][TN];
    #pragma unroll
    for (int i = 0; i < TM; ++i)
        #pragma unroll
        for (int j = 0; j < TN; ++j) acc[i][j] = 0.0f;
    for (int k0 = 0; k0 < GK; k0 += BK) {
        float4 av = *(const float4*)(Xp + k0);
        float4 bv = *(const float4*)(Wp + (size_t)k0 * GN);
        As[a_col4 + 0][a_row] = av.x;
        As[a_col4 + 1][a_row] = av.y;
        As[a_col4 + 2][a_row] = av.z;
        As[a_col4 + 3][a_row] = av.w;
        *(float4*)&Bs[b_row][b_col4] = bv;
        __syncthreads();
        #pragma unroll
        for (int k = 0; k < BK; ++k) {
            float4 a0 = *(const float4*)&As[k][ty * TM];
            float4 a1 = *(const float4*)&As[k][ty * TM + 4];
            float4 b0 = *(const float4*)&Bs[k][tx * TN];
            float4 b1 = *(const float4*)&Bs[k][tx * TN + 4];
            float ar[TM] = {a0.x, a0.y, a0.z, a0.w, a1.x, a1.y, a1.z, a1.w};
            float br[TN] = {b0.x, b0.y, b0.z, b0.w, b1.x, b1.y, b1.z, b1.w};
            #pragma unroll
            for (int i = 0; i < TM; ++i)
                #pragma unroll
                for (int j = 0; j < TN; ++j)
                    acc[i][j] = fmaf(ar[i], br[j], acc[i][j]);
        }
        __syncthreads();
    }
    #pragma unroll
    for (int i = 0; i < TM; ++i) {
        const int gr = row0 + ty * TM + i;
        float* yp = Y + (size_t)gr * GN + col0 + tx * TN;
        #pragma unroll
        for (int j = 0; j < TN; j += 4) {
            float4 v;
            v.x = acc[i][j + 0] + bias[col0 + tx * TN + j + 0];
            v.y = acc[i][j + 1] + bias[col0 + tx * TN + j + 1];
            v.z = acc[i][j + 2] + bias[col0 + tx * TN + j + 2];
            v.w = acc[i][j + 3] + bias[col0 + tx * TN + j + 3];
            *(float4*)(yp + j) = v;
        }
    }
}

// ---------------- FWHT + quantize: 2 rows/block, 256 thr x 16 elems/row -----
// 4096 = 16*16*16: three 4-bit register phases; ownership moved by padded-LDS
// transposes (pad p(e)=e+(e>>4) -> all access patterns conflict-free).
// R4: each block handles TWO rows; the same 5 barriers serve both rows
// (halves barrier count per row and block count).

__device__ __forceinline__ int pmap(int e) { return e + (e >> 4); }

__device__ __forceinline__ void bfly16(float v[16]) {
    #pragma unroll
    for (int h = 1; h < 16; h <<= 1)
        #pragma unroll
        for (int g = 0; g < 16; g += 2 * h)
            #pragma unroll
            for (int j = 0; j < h; ++j) {
                const float a = v[g + j], b = v[g + j + h];
                v[g + j] = a + b;
                v[g + j + h] = a - b;
            }
}

__global__ __launch_bounds__(256) void fwht_quant_kernel(float* __restrict__ Y)
{
    __shared__ float s[2][4096 + 256];
    const int t = threadIdx.x;
    float* yr[2];
    yr[0] = Y + (size_t)(2 * blockIdx.x) * GN;
    yr[1] = yr[0] + GN;

    // L1 ownership: e = 16*t + j (bits 0-3 in reg)
    float v[2][16];
    #pragma unroll
    for (int r = 0; r < 2; ++r) {
        if (t < 192) {
            #pragma unroll
            for (int q = 0; q < 4; ++q) {
                const float4 a = *(const float4*)(yr[r] + t * 16 + q * 4);
                v[r][q * 4 + 0] = a.x; v[r][q * 4 + 1] = a.y;
                v[r][q * 4 + 2] = a.z; v[r][q * 4 + 3] = a.w;
            }
        } else {
            #pragma unroll
            for (int j = 0; j < 16; ++j) v[r][j] = 0.0f;
        }
    }

    #pragma unroll
    for (int r = 0; r < 2; ++r) bfly16(v[r]);    // bits 0-3

    #pragma unroll
    for (int r = 0; r < 2; ++r)
        #pragma unroll
        for (int j = 0; j < 16; ++j) s[r][pmap(t * 16 + j)] = v[r][j];
    __syncthreads();
    // L2 ownership: e = (t&15) + 16*j + 256*(t>>4) (bits 4-7 in reg)
    #pragma unroll
    for (int r = 0; r < 2; ++r)
        #pragma unroll
        for (int j = 0; j < 16; ++j) v[r][j] = s[r][pmap((t & 15) + 16 * j + 256 * (t >> 4))];

    #pragma unroll
    for (int r = 0; r < 2; ++r) bfly16(v[r]);    // bits 4-7

    // write back to own L2 cells (no barrier needed: same cells we just read)
    #pragma unroll
    for (int r = 0; r < 2; ++r)
        #pragma unroll
        for (int j = 0; j < 16; ++j) s[r][pmap((t & 15) + 16 * j + 256 * (t >> 4))] = v[r][j];
    __syncthreads();
    // L3 ownership: e = t + 256*j (bits 8-11 in reg)
    #pragma unroll
    for (int r = 0; r < 2; ++r)
        #pragma unroll
        for (int j = 0; j < 16; ++j) v[r][j] = s[r][pmap(t + 256 * j)];

    #pragma unroll
    for (int r = 0; r < 2; ++r) {
        bfly16(v[r]);                            // bits 8-11: forward done (unnormalized)
        #pragma unroll
        for (int j = 0; j < 16; ++j) {           // idx = clip(round((v/64)/0.25), -8, 7)
            float idx = rintf(v[r][j] * 0.0625f);
            idx = fminf(fmaxf(idx, -8.0f), 7.0f);
            v[r][j] = idx * 0.25f;
        }
        bfly16(v[r]);                            // inverse bits 8-11
    }

    #pragma unroll
    for (int r = 0; r < 2; ++r)
        #pragma unroll
        for (int j = 0; j < 16; ++j) s[r][pmap(t + 256 * j)] = v[r][j];
    __syncthreads();
    #pragma unroll
    for (int r = 0; r < 2; ++r)
        #pragma unroll
        for (int j = 0; j < 16; ++j) v[r][j] = s[r][pmap((t & 15) + 16 * j + 256 * (t >> 4))];

    #pragma unroll
    for (int r = 0; r < 2; ++r) bfly16(v[r]);    // inverse bits 4-7

    #pragma unroll
    for (int r = 0; r < 2; ++r)
        #pragma unroll
        for (int j = 0; j < 16; ++j) s[r][pmap((t & 15) + 16 * j + 256 * (t >> 4))] = v[r][j];
    __syncthreads();
    #pragma unroll
    for (int r = 0; r < 2; ++r)
        #pragma unroll
        for (int j = 0; j < 16; ++j) v[r][j] = s[r][pmap(t * 16 + j)];

    #pragma unroll
    for (int r = 0; r < 2; ++r) bfly16(v[r]);    // inverse bits 0-3

    if (t < 192) {
        const float sc = 0.015625f;
        #pragma unroll
        for (int r = 0; r < 2; ++r)
            #pragma unroll
            for (int q = 0; q < 4; ++q) {
                float4 a = make_float4(v[r][q * 4 + 0] * sc, v[r][q * 4 + 1] * sc,
                                       v[r][q * 4 + 2] * sc, v[r][q * 4 + 3] * sc);
                *(float4*)(yr[r] + t * 16 + q * 4) = a;
            }
    }
}

// ---------------- launch ----------------

extern "C" void kernel_launch(void* const* d_in, const int* in_sizes, int n_in,
                              void* d_out, int out_size, void* d_ws, size_t ws_size,
                              hipStream_t stream) {
    const float* X    = (const float*)d_in[0];   // 8192 x 4096
    const float* W    = (const float*)d_in[1];   // 4096 x 3072
    const float* bias = (const float*)d_in[2];   // 3072
    float* out = (float*)d_out;                  // 8192 x 3072

    const size_t SZ_XH = (size_t)GM * GK * sizeof(f16);  // 64 MB
    const size_t SZ_WT = (size_t)GN * GK * sizeof(f16);  // 24 MB
    const size_t need  = SZ_XH + SZ_WT;                  // 88 MB

    if (ws_size >= need) {
        f16* Xh = (f16*)d_ws;
        f16* WT = (f16*)((char*)d_ws + SZ_XH);

        split_x_kernel<<<(GM * (size_t)GK) / (8 * 256), 256, 0, stream>>>(X, Xh);
        split_wt_kernel<<<dim3(GN / 32, GK / 32), 256, 0, stream>>>(W, WT);
        gemm_f16_kernel<<<dim3(GN / 128, GM / 128), 256, 0, stream>>>(Xh, WT, bias, out);
    } else {
        gemm_bias_kernel<<<dim3(GN / BN, GM / BM), 256, 0, stream>>>(X, W, bias, out);
    }

    fwht_quant_kernel<<<GM / 2, 256, 0, stream>>>(out);
}

// Round 5
// 504.932 us; speedup vs baseline: 1.2107x; 1.0342x over previous
//
#include <hip/hip_runtime.h>
#include <hip/hip_bf16.h>
#include <stdint.h>

// y = X(8192x4096) @ W(4096x3072) + b, then rotor quantizer:
// out = fwht(clip(round(fwht(pad(y))/64/0.25),-8,7)*0.25)/64, first 3072 cols.
//
// GEMM: single fp16 MFMA (32x32x16), fp32 accumulate (R0 structure, verified
// 228 us / MfmaUtil 43%; all hand-pipelined variants R1-R3 regressed).
//
// R5: (a) fwht back to 1 row/block (R4's 2-row variant cost ~19 us via halved
// occupancy); (b) Y stored as f16 in workspace when it fits (saves ~96 MB HBM:
// 48 gemm-write + 48 fwht-read); (c) split_x+split_wt fused into one dispatch.

#define GM 8192
#define GN 3072
#define GK 4096

typedef _Float16 f16;
typedef __attribute__((ext_vector_type(8))) _Float16 f16x8;   // 4 VGPRs
typedef __attribute__((ext_vector_type(16))) float f32x16;

__device__ __forceinline__ void gl2lds16(const void* g, void* l) {
    __builtin_amdgcn_global_load_lds(
        (const __attribute__((address_space(1))) void*)g,
        (__attribute__((address_space(3))) void*)l, 16, 0, 0);
}

// ---------------- fused cast / transpose pre-pass ----------------
// blocks [0, NXBLK): X f32 -> Xh f16 (streaming cast)
// blocks [NXBLK, NXBLK+NWBLK): W (4096k x 3072n) -> WT (3072n x 4096k) f16

#define NXBLK 16384   // GM*GK/(8*256)
#define NWBLK 12288   // (GN/32)*(GK/32)

struct alignas(16) H8 { f16 v[8]; };

__global__ __launch_bounds__(256) void prepass_kernel(
    const float* __restrict__ X, f16* __restrict__ Xh,
    const float* __restrict__ W, f16* __restrict__ WT)
{
    __shared__ float tile[32][33];
    const int b = blockIdx.x;
    if (b < NXBLK) {
        const size_t i = ((size_t)b * 256 + threadIdx.x) * 8;
        const float4 a = *(const float4*)(X + i);
        const float4 c = *(const float4*)(X + i + 4);
        H8 h;
        h.v[0] = (f16)a.x; h.v[1] = (f16)a.y; h.v[2] = (f16)a.z; h.v[3] = (f16)a.w;
        h.v[4] = (f16)c.x; h.v[5] = (f16)c.y; h.v[6] = (f16)c.z; h.v[7] = (f16)c.w;
        *(H8*)(Xh + i) = h;
    } else {
        const int b2 = b - NXBLK;
        const int nt = (b2 % 96) * 32;
        const int kt = (b2 / 96) * 32;
        const int tx = threadIdx.x & 31;
        const int ty = threadIdx.x >> 5;   // 0..7
        #pragma unroll
        for (int r = 0; r < 4; ++r)
            tile[ty + 8 * r][tx] = W[(size_t)(kt + ty + 8 * r) * GN + nt + tx];
        __syncthreads();
        #pragma unroll
        for (int r = 0; r < 4; ++r)
            WT[(size_t)(nt + ty + 8 * r) * GK + kt + tx] = (f16)tile[tx][ty + 8 * r];
    }
}

// ---------------- fp16 MFMA GEMM (32x32x16), 128x128 tile, BK=64 ----------------
// (R0 structure, verified 228 us / MfmaUtil 43%.)
// LDS rows: 64 halfs (128 B) = 8 x 16-B slots, XOR-swizzled: phys = s ^ (row&7).
// 4 waves (2x2), each wave 64x64 as 2x2 of 32x32 accs, 16 MFMA per barrier.
// Output: f32 (Y=out) or f16 (Y=workspace) selected by uniform flag.

__global__ __launch_bounds__(256) void gemm_f16_kernel(
    const f16* __restrict__ Xh, const f16* __restrict__ WT,
    const float* __restrict__ bias, void* __restrict__ Yv, int f16out)
{
    __shared__ __align__(16) f16 sA[128 * 64];
    __shared__ __align__(16) f16 sB[128 * 64];

    const int tid  = threadIdx.x;
    const int wave = tid >> 6;
    const int lane = tid & 63;
    const int half = lane >> 5;   // k-half selector (0/1)
    const int l32  = lane & 31;
    const int wm   = (wave & 1) * 64;
    const int wn   = (wave >> 1) * 64;

    const int row0 = blockIdx.y * 128;
    const int col0 = blockIdx.x * 128;

    // staging: each gl2lds16 instr writes 8 rows (64 lanes x 16B = 1 KB).
    // lane -> row base+(lane>>3), phys slot lane&7; logical slot = (l&7)^((l>>3)&7).
    const int lr8 = lane >> 3;                              // 0..7
    const int lc  = ((lane & 7) ^ ((lane >> 3) & 7)) * 8;   // global col (halfs)

    const f16* gA[4];
    const f16* gB[4];
    f16* dA[4];
    f16* dB[4];
    #pragma unroll
    for (int q = 0; q < 4; ++q) {
        const int g = wave * 4 + q;        // 8-row group index 0..15
        gA[q] = Xh + (size_t)(row0 + g * 8 + lr8) * GK + lc;
        gB[q] = WT + (size_t)(col0 + g * 8 + lr8) * GK + lc;
        dA[q] = &sA[g * 512];
        dB[q] = &sB[g * 512];
    }

    // fragment LDS offsets: [tile i][ksub 0..3]
    int offA[2][4], offB[2][4];
    #pragma unroll
    for (int i = 0; i < 2; ++i)
        #pragma unroll
        for (int ks = 0; ks < 4; ++ks) {
            const int rA = wm + i * 32 + l32;
            const int rB = wn + i * 32 + l32;
            offA[i][ks] = rA * 64 + (((ks * 2 + half) ^ (rA & 7)) * 8);
            offB[i][ks] = rB * 64 + (((ks * 2 + half) ^ (rB & 7)) * 8);
        }

    f32x16 acc[2][2];
    #pragma unroll
    for (int i = 0; i < 2; ++i)
        #pragma unroll
        for (int j = 0; j < 2; ++j)
            acc[i][j] = (f32x16)0.0f;

    for (int k0 = 0; k0 < GK; k0 += 64) {
        #pragma unroll
        for (int q = 0; q < 4; ++q) {
            gl2lds16(gA[q] + k0, dA[q]);
            gl2lds16(gB[q] + k0, dB[q]);
        }
        __syncthreads();

        f16x8 af[2][4], bf[2][4];
        #pragma unroll
        for (int i = 0; i < 2; ++i)
            #pragma unroll
            for (int ks = 0; ks < 4; ++ks) {
                af[i][ks] = *(const f16x8*)&sA[offA[i][ks]];
                bf[i][ks] = *(const f16x8*)&sB[offB[i][ks]];
            }
        #pragma unroll
        for (int ks = 0; ks < 4; ++ks)
            #pragma unroll
            for (int i = 0; i < 2; ++i)
                #pragma unroll
                for (int j = 0; j < 2; ++j)
                    acc[i][j] = __builtin_amdgcn_mfma_f32_32x32x16_f16(af[i][ks], bf[j][ks], acc[i][j], 0, 0, 0);
        __syncthreads();
    }

    // epilogue: C/D layout col=lane&31, row=(reg&3)+8*(reg>>2)+4*(lane>>5)
    if (f16out) {
        f16* Y = (f16*)Yv;
        #pragma unroll
        for (int i = 0; i < 2; ++i)
            #pragma unroll
            for (int j = 0; j < 2; ++j) {
                const int c = col0 + wn + j * 32 + l32;
                const float bv = bias[c];
                #pragma unroll
                for (int r = 0; r < 16; ++r) {
                    const int rw = row0 + wm + i * 32 + (r & 3) + 8 * (r >> 2) + 4 * half;
                    Y[(size_t)rw * GN + c] = (f16)(acc[i][j][r] + bv);
                }
            }
    } else {
        float* Y = (float*)Yv;
        #pragma unroll
        for (int i = 0; i < 2; ++i)
            #pragma unroll
            for (int j = 0; j < 2; ++j) {
                const int c = col0 + wn + j * 32 + l32;
                const float bv = bias[c];
                #pragma unroll
                for (int r = 0; r < 16; ++r) {
                    const int rw = row0 + wm + i * 32 + (r & 3) + 8 * (r >> 2) + 4 * half;
                    Y[(size_t)rw * GN + c] = acc[i][j][r] + bv;
                }
            }
    }
}

// ---------------- fp32 fallback GEMM (if workspace too small) ----------------

#define BM 128
#define BN 128
#define BK 8
#define TM 8
#define TN 8

__global__ __launch_bounds__(256) void gemm_bias_kernel(
    const float* __restrict__ X, const float* __restrict__ W,
    const float* __restrict__ bias, float* __restrict__ Y)
{
    __shared__ float As[BK][BM];
    __shared__ float Bs[BK][BN];
    const int tid = threadIdx.x;
    const int row0 = blockIdx.y * BM;
    const int col0 = blockIdx.x * BN;
    const int a_row = tid >> 1, a_col4 = (tid & 1) * 4;
    const int b_row = tid >> 5, b_col4 = (tid & 31) * 4;
    const int tx = tid & 15, ty = tid >> 4;
    const float* Xp = X + (size_t)(row0 + a_row) * GK + a_col4;
    const float* Wp = W + (size_t)b_row * GN + (col0 + b_col4);
    float acc[TM][TN];
    #pragma unroll
    for (int i = 0; i < TM; ++i)
        #pragma unroll
        for (int j = 0; j < TN; ++j) acc[i][j] = 0.0f;
    for (int k0 = 0; k0 < GK; k0 += BK) {
        float4 av = *(const float4*)(Xp + k0);
        float4 bv = *(const float4*)(Wp + (size_t)k0 * GN);
        As[a_col4 + 0][a_row] = av.x;
        As[a_col4 + 1][a_row] = av.y;
        As[a_col4 + 2][a_row] = av.z;
        As[a_col4 + 3][a_row] = av.w;
        *(float4*)&Bs[b_row][b_col4] = bv;
        __syncthreads();
        #pragma unroll
        for (int k = 0; k < BK; ++k) {
            float4 a0 = *(const float4*)&As[k][ty * TM];
            float4 a1 = *(const float4*)&As[k][ty * TM + 4];
            float4 b0 = *(const float4*)&Bs[k][tx * TN];
            float4 b1 = *(const float4*)&Bs[k][tx * TN + 4];
            float ar[TM] = {a0.x, a0.y, a0.z, a0.w, a1.x, a1.y, a1.z, a1.w};
            float br[TN] = {b0.x, b0.y, b0.z, b0.w, b1.x, b1.y, b1.z, b1.w};
            #pragma unroll
            for (int i = 0; i < TM; ++i)
                #pragma unroll
                for (int j = 0; j < TN; ++j)
                    acc[i][j] = fmaf(ar[i], br[j], acc[i][j]);
        }
        __syncthreads();
    }
    #pragma unroll
    for (int i = 0; i < TM; ++i) {
        const int gr = row0 + ty * TM + i;
        float* yp = Y + (size_t)gr * GN + col0 + tx * TN;
        #pragma unroll
        for (int j = 0; j < TN; j += 4) {
            float4 v;
            v.x = acc[i][j + 0] + bias[col0 + tx * TN + j + 0];
            v.y = acc[i][j + 1] + bias[col0 + tx * TN + j + 1];
            v.z = acc[i][j + 2] + bias[col0 + tx * TN + j + 2];
            v.w = acc[i][j + 3] + bias[col0 + tx * TN + j + 3];
            *(float4*)(yp + j) = v;
        }
    }
}

// ---------------- FWHT + quantize: 256 thr x 16 elems, register butterflies ----
// 4096 = 16*16*16: three 4-bit register phases; ownership moved by padded-LDS
// transposes (pad p(e)=e+(e>>4) -> all access patterns conflict-free).
// No shuffles; 4 barriers total. Shared body; input loaded by the callers.

__device__ __forceinline__ int pmap(int e) { return e + (e >> 4); }

__device__ __forceinline__ void bfly16(float v[16]) {
    #pragma unroll
    for (int h = 1; h < 16; h <<= 1)
        #pragma unroll
        for (int g = 0; g < 16; g += 2 * h)
            #pragma unroll
            for (int j = 0; j < h; ++j) {
                const float a = v[g + j], b = v[g + j + h];
                v[g + j] = a + b;
                v[g + j + h] = a - b;
            }
}

__device__ __forceinline__ void fwht_quant_body(
    float v[16], float* __restrict__ s, int t, float* __restrict__ orow)
{
    bfly16(v);                                   // bits 0-3

    #pragma unroll
    for (int j = 0; j < 16; ++j) s[pmap(t * 16 + j)] = v[j];
    __syncthreads();
    // L2 ownership: e = (t&15) + 16*j + 256*(t>>4) (bits 4-7 in reg)
    #pragma unroll
    for (int j = 0; j < 16; ++j) v[j] = s[pmap((t & 15) + 16 * j + 256 * (t >> 4))];

    bfly16(v);                                   // bits 4-7

    // write back to own L2 cells (no barrier needed: same cells we just read)
    #pragma unroll
    for (int j = 0; j < 16; ++j) s[pmap((t & 15) + 16 * j + 256 * (t >> 4))] = v[j];
    __syncthreads();
    // L3 ownership: e = t + 256*j (bits 8-11 in reg)
    #pragma unroll
    for (int j = 0; j < 16; ++j) v[j] = s[pmap(t + 256 * j)];

    bfly16(v);                                   // bits 8-11: forward done (unnormalized)

    #pragma unroll
    for (int j = 0; j < 16; ++j) {               // idx = clip(round((v/64)/0.25), -8, 7)
        float idx = rintf(v[j] * 0.0625f);
        idx = fminf(fmaxf(idx, -8.0f), 7.0f);
        v[j] = idx * 0.25f;
    }

    bfly16(v);                                   // inverse bits 8-11

    #pragma unroll
    for (int j = 0; j < 16; ++j) s[pmap(t + 256 * j)] = v[j];
    __syncthreads();
    #pragma unroll
    for (int j = 0; j < 16; ++j) v[j] = s[pmap((t & 15) + 16 * j + 256 * (t >> 4))];

    bfly16(v);                                   // inverse bits 4-7

    #pragma unroll
    for (int j = 0; j < 16; ++j) s[pmap((t & 15) + 16 * j + 256 * (t >> 4))] = v[j];
    __syncthreads();
    #pragma unroll
    for (int j = 0; j < 16; ++j) v[j] = s[pmap(t * 16 + j)];

    bfly16(v);                                   // inverse bits 0-3

    if (t < 192) {
        const float sc = 0.015625f;
        #pragma unroll
        for (int q = 0; q < 4; ++q) {
            float4 a = make_float4(v[q * 4 + 0] * sc, v[q * 4 + 1] * sc,
                                   v[q * 4 + 2] * sc, v[q * 4 + 3] * sc);
            *(float4*)(orow + t * 16 + q * 4) = a;
        }
    }
}

// f32 in-place variant (Y == out)
__global__ __launch_bounds__(256) void fwht_quant_kernel(float* __restrict__ Y)
{
    __shared__ float s[4096 + 256];
    const int t = threadIdx.x;
    float* yrow = Y + (size_t)blockIdx.x * GN;

    float v[16];
    if (t < 192) {
        #pragma unroll
        for (int q = 0; q < 4; ++q) {
            const float4 a = *(const float4*)(yrow + t * 16 + q * 4);
            v[q * 4 + 0] = a.x; v[q * 4 + 1] = a.y;
            v[q * 4 + 2] = a.z; v[q * 4 + 3] = a.w;
        }
    } else {
        #pragma unroll
        for (int j = 0; j < 16; ++j) v[j] = 0.0f;
    }
    fwht_quant_body(v, s, t, yrow);
}

// f16-input variant (Yh in workspace -> f32 out)
__global__ __launch_bounds__(256) void fwht_quant_f16_kernel(
    const f16* __restrict__ Yh, float* __restrict__ out)
{
    __shared__ float s[4096 + 256];
    const int t = threadIdx.x;
    const f16* yrow = Yh + (size_t)blockIdx.x * GN;
    float* orow = out + (size_t)blockIdx.x * GN;

    float v[16];
    if (t < 192) {
        const f16x8 a = *(const f16x8*)(yrow + t * 16);
        const f16x8 b = *(const f16x8*)(yrow + t * 16 + 8);
        #pragma unroll
        for (int j = 0; j < 8; ++j) {
            v[j]     = (float)a[j];
            v[8 + j] = (float)b[j];
        }
    } else {
        #pragma unroll
        for (int j = 0; j < 16; ++j) v[j] = 0.0f;
    }
    fwht_quant_body(v, s, t, orow);
}

// ---------------- launch ----------------

extern "C" void kernel_launch(void* const* d_in, const int* in_sizes, int n_in,
                              void* d_out, int out_size, void* d_ws, size_t ws_size,
                              hipStream_t stream) {
    const float* X    = (const float*)d_in[0];   // 8192 x 4096
    const float* W    = (const float*)d_in[1];   // 4096 x 3072
    const float* bias = (const float*)d_in[2];   // 3072
    float* out = (float*)d_out;                  // 8192 x 3072

    const size_t SZ_XH = (size_t)GM * GK * sizeof(f16);  // 64 MB
    const size_t SZ_WT = (size_t)GN * GK * sizeof(f16);  // 24 MB
    const size_t SZ_YH = (size_t)GM * GN * sizeof(f16);  // 48 MB

    if (ws_size >= SZ_XH + SZ_WT + SZ_YH) {
        // full pipeline: f16 staging + f16 Y in workspace
        f16* Xh = (f16*)d_ws;
        f16* WT = (f16*)((char*)d_ws + SZ_XH);
        f16* Yh = (f16*)((char*)d_ws + SZ_XH + SZ_WT);

        prepass_kernel<<<NXBLK + NWBLK, 256, 0, stream>>>(X, Xh, W, WT);
        gemm_f16_kernel<<<dim3(GN / 128, GM / 128), 256, 0, stream>>>(Xh, WT, bias, Yh, 1);
        fwht_quant_f16_kernel<<<GM, 256, 0, stream>>>(Yh, out);
    } else if (ws_size >= SZ_XH + SZ_WT) {
        // R0-equivalent: f16 staging, f32 Y in out, in-place fwht
        f16* Xh = (f16*)d_ws;
        f16* WT = (f16*)((char*)d_ws + SZ_XH);

        prepass_kernel<<<NXBLK + NWBLK, 256, 0, stream>>>(X, Xh, W, WT);
        gemm_f16_kernel<<<dim3(GN / 128, GM / 128), 256, 0, stream>>>(Xh, WT, bias, out, 0);
        fwht_quant_kernel<<<GM, 256, 0, stream>>>(out);
    } else {
        gemm_bias_kernel<<<dim3(GN / BN, GM / BM), 256, 0, stream>>>(X, W, bias, out);
        fwht_quant_kernel<<<GM, 256, 0, stream>>>(out);
    }
}